// Round 1
// baseline (69.618 us; speedup 1.0000x reference)
//
#include <hip/hip_runtime.h>
#include <math.h>

#define NDET 16
#define NDIM 16

// One 16x16 LU with partial pivoting per 4-lane group.
// Lane l of the group owns columns 4l..4l+3 : c[j][i] = M[i][4l+j].
// All register indices are compile-time (full unroll) -> stays in VGPRs.

__global__ __launch_bounds__(256) void logabssumdet_kernel(
    const float* __restrict__ a,
    const float* __restrict__ b,
    const float* __restrict__ w,
    float* __restrict__ out,
    int n_samples)
{
    const int tid   = threadIdx.x;
    const int lane4 = tid & 3;
    const int group = tid >> 2;                        // 0..63 in block
    const int mat_id = blockIdx.x * 64 + group;        // = sample*16 + det
    const int n_mats = n_samples * NDET;

    __shared__ float sx[64];
    __shared__ float ss[64];

    float x = 0.0f, sgn_all = 1.0f;

    if (mat_id < n_mats) {
        #pragma unroll 1   // keep one copy of the LU body (I-cache)
        for (int m = 0; m < 2; ++m) {
            const float* src = (m == 0) ? a : b;
            const float4* mb =
                reinterpret_cast<const float4*>(src + (size_t)mat_id * (NDIM * NDIM)) + lane4;

            float c[4][16];
            #pragma unroll
            for (int i = 0; i < 16; ++i) {
                float4 v = mb[i * 4];                  // 64B contiguous per 4-lane group
                c[0][i] = v.x; c[1][i] = v.y; c[2][i] = v.z; c[3][i] = v.w;
            }

            float logdet = 0.0f, sg = 1.0f;
            #pragma unroll
            for (int k = 0; k < 16; ++k) {
                const int owner = k >> 2;              // lane owning column k
                const int kc    = k & 3;               // its local column index

                // --- pivot search (meaningful on owner lane only; SIMT-redundant elsewhere)
                float best = fabsf(c[kc][k]);
                int   pidx = k;
                #pragma unroll
                for (int i = k + 1; i < 16; ++i) {
                    float v  = fabsf(c[kc][i]);
                    bool  bt = v > best;
                    best = bt ? v : best;
                    pidx = bt ? i : pidx;
                }
                pidx = __shfl(pidx, owner, 4);
                sg = (pidx != k) ? -sg : sg;

                // --- row swap k <-> pidx via cndmask chain (no-op when pidx==k)
                #pragma unroll
                for (int i = k + 1; i < 16; ++i) {
                    bool msel = (i == pidx);
                    #pragma unroll
                    for (int j = 0; j < 4; ++j) {
                        float tk = c[j][k], ti = c[j][i];
                        c[j][k] = msel ? ti : tk;
                        c[j][i] = msel ? tk : ti;
                    }
                }

                // --- pivot, sign, log-accumulate
                float pivot = __shfl(c[kc][k], owner, 4);
                sg = (pivot < 0.0f) ? -sg : sg;
                logdet += __logf(fabsf(pivot));
                float rp = __builtin_amdgcn_rcpf(pivot);
                rp = rp * (2.0f - pivot * rp);         // one NR refine, ~1e-7 rel

                // --- elimination of rows k+1..15
                #pragma unroll
                for (int i = k + 1; i < 16; ++i) {
                    float mik = __shfl(c[kc][i], owner, 4) * rp;
                    #pragma unroll
                    for (int j = 0; j < 4; ++j)
                        c[j][i] = fmaf(-mik, c[j][k], c[j][i]);
                }
            }
            x += logdet;
            sgn_all *= sg;
        }
    }

    if (lane4 == 0) { sx[group] = x; ss[group] = sgn_all; }
    __syncthreads();

    // 4 samples per block; one thread finishes each sample's 16-det LSE
    if (tid < 4) {
        const int sample = blockIdx.x * 4 + tid;
        if (sample < n_samples) {
            const int base = tid * NDET;
            float xmax = -INFINITY;
            #pragma unroll
            for (int d = 0; d < NDET; ++d) xmax = fmaxf(xmax, sx[base + d]);
            float sum = 0.0f;
            #pragma unroll
            for (int d = 0; d < NDET; ++d)
                sum += ss[base + d] * __expf(sx[base + d] - xmax) * w[d];
            out[sample] = __logf(fabsf(sum)) + xmax;
            out[n_samples + sample] = (sum > 0.0f) ? 1.0f : ((sum < 0.0f) ? -1.0f : 0.0f);
        }
    }
}

extern "C" void kernel_launch(void* const* d_in, const int* in_sizes, int n_in,
                              void* d_out, int out_size, void* d_ws, size_t ws_size,
                              hipStream_t stream)
{
    const float* a = (const float*)d_in[0];
    const float* b = (const float*)d_in[1];
    const float* w = (const float*)d_in[2];
    float* out = (float*)d_out;

    const int n_samples = in_sizes[0] / (NDET * NDIM * NDIM);
    const int blocks = (n_samples + 3) / 4;   // 4 samples (64 matrices... 64 dets) per block
    logabssumdet_kernel<<<blocks, 256, 0, stream>>>(a, b, w, out, n_samples);
}

// Round 2
// 59.529 us; speedup vs baseline: 1.1695x; 1.1695x over previous
//
#include <hip/hip_runtime.h>
#include <math.h>

#define NDET 16
#define NDIM 16

// Quad (4-lane) broadcast via DPP quad_perm — pure VALU, no LDS path.
// OWNER must be a compile-time constant (template param).
template<int OWNER>
__device__ __forceinline__ float bcast4f(float v) {
    constexpr int ctrl = OWNER * 0x55;  // quad_perm:[OWNER,OWNER,OWNER,OWNER]
    return __int_as_float(
        __builtin_amdgcn_mov_dpp(__float_as_int(v), ctrl, 0xF, 0xF, true));
}
template<int OWNER>
__device__ __forceinline__ int bcast4i(int v) {
    constexpr int ctrl = OWNER * 0x55;
    return __builtin_amdgcn_mov_dpp(v, ctrl, 0xF, 0xF, true);
}

// One LU step (column K) of a 16x16 matrix spread over a 4-lane quad:
// lane l owns global columns 4l..4l+3 as c[j][row].  Fully compile-time
// indexed -> everything stays in VGPRs.
template<int K>
__device__ __forceinline__ void lu_step(float (&c)[4][16], float &prod, int &nswap) {
    constexpr int OWNER = K >> 2;   // lane owning column K
    constexpr int KC    = K & 3;    // its local column index

    if constexpr (K < 15) {
        // --- argmax |c[KC][i]| for i in [K,15] via packed uint key (monotone for |x|)
        unsigned key = (__float_as_uint(fabsf(c[KC][K])) & ~15u) | (unsigned)K;
        #pragma unroll
        for (int i = K + 1; i < 16; ++i) {
            unsigned ki = (__float_as_uint(fabsf(c[KC][i])) & ~15u) | (unsigned)i;
            key = key > ki ? key : ki;
        }
        const int pidx = bcast4i<OWNER>((int)(key & 15u));
        nswap += (pidx != K) ? 1 : 0;

        // --- row swap K <-> pidx (cndmask chain; no-op when pidx==K)
        #pragma unroll
        for (int i = K + 1; i < 16; ++i) {
            const bool msel = (i == pidx);
            #pragma unroll
            for (int j = 0; j < 4; ++j) {
                float tk = c[j][K], ti = c[j][i];
                c[j][K] = msel ? ti : tk;
                c[j][i] = msel ? tk : ti;
            }
        }
    }

    const float pivot = bcast4f<OWNER>(c[KC][K]);
    prod *= pivot;                   // one logf at the end instead of 16

    if constexpr (K < 15) {
        const float rp = __builtin_amdgcn_rcpf(pivot);  // 1e-7 rel is plenty
        #pragma unroll
        for (int i = K + 1; i < 16; ++i) {
            const float mik = bcast4f<OWNER>(c[KC][i]) * rp;
            #pragma unroll
            for (int j = 0; j < 4; ++j)
                c[j][i] = fmaf(-mik, c[j][K], c[j][i]);
        }
    }
}

template<int K>
__device__ __forceinline__ void lu_all(float (&c)[4][16], float &prod, int &nswap) {
    lu_step<K>(c, prod, nswap);
    if constexpr (K < 15) lu_all<K + 1>(c, prod, nswap);
}

__global__ __launch_bounds__(256) void logabssumdet_kernel(
    const float* __restrict__ a,
    const float* __restrict__ b,
    const float* __restrict__ w,
    float* __restrict__ out,
    int n_samples)
{
    const int tid    = threadIdx.x;
    const int lane4  = tid & 3;
    const int group  = tid >> 2;                    // 0..63 in block
    const int mat_id = blockIdx.x * 64 + group;     // = sample*16 + det
    const int n_mats = n_samples * NDET;

    __shared__ float sx[64];
    __shared__ float ss[64];

    float x = 0.0f, sgn_all = 1.0f;

    if (mat_id < n_mats) {
        #pragma unroll 1   // one copy of the LU body
        for (int m = 0; m < 2; ++m) {
            const float* src = (m == 0) ? a : b;
            const float4* mb =
                reinterpret_cast<const float4*>(src + (size_t)mat_id * (NDIM * NDIM)) + lane4;

            float c[4][16];
            #pragma unroll
            for (int i = 0; i < 16; ++i) {
                float4 v = mb[i * 4];               // 64B contiguous per quad
                c[0][i] = v.x; c[1][i] = v.y; c[2][i] = v.z; c[3][i] = v.w;
            }

            float prod = 1.0f;
            int nswap = 0;
            lu_all<0>(c, prod, nswap);

            x += __logf(fabsf(prod));
            sgn_all = (prod < 0.0f) ? -sgn_all : sgn_all;
            sgn_all = (nswap & 1) ? -sgn_all : sgn_all;
        }
    }

    if (lane4 == 0) { sx[group] = x; ss[group] = sgn_all; }
    __syncthreads();

    // 4 samples per block; one thread finishes each sample's 16-det LSE
    if (tid < 4) {
        const int sample = blockIdx.x * 4 + tid;
        if (sample < n_samples) {
            const int base = tid * NDET;
            float xmax = -INFINITY;
            #pragma unroll
            for (int d = 0; d < NDET; ++d) xmax = fmaxf(xmax, sx[base + d]);
            float sum = 0.0f;
            #pragma unroll
            for (int d = 0; d < NDET; ++d)
                sum += ss[base + d] * __expf(sx[base + d] - xmax) * w[d];
            out[sample] = __logf(fabsf(sum)) + xmax;
            out[n_samples + sample] = (sum > 0.0f) ? 1.0f : ((sum < 0.0f) ? -1.0f : 0.0f);
        }
    }
}

extern "C" void kernel_launch(void* const* d_in, const int* in_sizes, int n_in,
                              void* d_out, int out_size, void* d_ws, size_t ws_size,
                              hipStream_t stream)
{
    const float* a = (const float*)d_in[0];
    const float* b = (const float*)d_in[1];
    const float* w = (const float*)d_in[2];
    float* out = (float*)d_out;

    const int n_samples = in_sizes[0] / (NDET * NDIM * NDIM);
    const int blocks = (n_samples + 3) / 4;   // 4 samples (64 dets) per block
    logabssumdet_kernel<<<blocks, 256, 0, stream>>>(a, b, w, out, n_samples);
}